// Round 1
// baseline (813.291 us; speedup 1.0000x reference)
//
#include <hip/hip_runtime.h>

#define SENSOR_W 640
#define SENSOR_H 480
#define HW (SENSOR_W * SENSOR_H)

// Copy event_image (the additive base) into d_out. out = event_image + counts.
__global__ void init_out_kernel(const float* __restrict__ event_image,
                                float* __restrict__ out, int n) {
    int i = blockIdx.x * blockDim.x + threadIdx.x;
    int stride = gridDim.x * blockDim.x;
    for (; i < n; i += stride) {
        out[i] = event_image[i];
    }
}

// Scatter: one event per grid-stride iteration. Coalesced float4 loads.
__global__ void event_scatter_kernel(const float4* __restrict__ events,
                                     float* __restrict__ out, int n_events) {
    int i = blockIdx.x * blockDim.x + threadIdx.x;
    int stride = gridDim.x * blockDim.x;
    for (; i < n_events; i += stride) {
        float4 ev = events[i];            // x, y, t, p
        int x = (int)ev.x;                // astype(int32) == trunc
        int y = (int)ev.y;
        bool valid = (x >= 0) & (x < SENSOR_W) & (y >= 0) & (y < SENSOR_H);
        if (valid) {
            int ch = (ev.w > 0.0f) ? 0 : 1;   // pos -> channel 0, neg -> channel 1
            atomicAdd(&out[ch * HW + y * SENSOR_W + x], 1.0f);
        }
    }
}

extern "C" void kernel_launch(void* const* d_in, const int* in_sizes, int n_in,
                              void* d_out, int out_size, void* d_ws, size_t ws_size,
                              hipStream_t stream) {
    const float4* events = (const float4*)d_in[0];
    const float* event_image = (const float*)d_in[1];
    float* out = (float*)d_out;

    int n_events = in_sizes[0] / 4;       // in_sizes[0] counts flat floats (N x 4)
    int n_out = out_size;                 // 2*480*640 = 614400

    // 1) initialize output with the additive base image
    {
        int block = 256;
        int grid = (n_out + block - 1) / block;   // 2400 blocks
        init_out_kernel<<<grid, block, 0, stream>>>(event_image, out, n_out);
    }

    // 2) scatter events with global atomics
    {
        int block = 256;
        int grid = 2048;                  // grid-stride; 8 wg/CU across 256 CUs
        event_scatter_kernel<<<grid, block, 0, stream>>>(events, out, n_events);
    }
}

// Round 2
// 642.599 us; speedup vs baseline: 1.2656x; 1.2656x over previous
//
#include <hip/hip_runtime.h>

#define SENSOR_W 640
#define SENSOR_H 480
#define HW (SENSOR_W * SENSOR_H)
#define N_OUT (2 * HW)

// Phase 1: zero the output buffer (it will hold uint32 counters).
__global__ void zero_kernel(unsigned* __restrict__ cnt, int n) {
    int i = blockIdx.x * blockDim.x + threadIdx.x;
    int stride = gridDim.x * blockDim.x;
    for (; i < n; i += stride) cnt[i] = 0u;
}

// Phase 2: scatter with NATIVE integer atomics (no FP CAS loop).
__global__ void event_scatter_kernel(const float4* __restrict__ events,
                                     unsigned* __restrict__ cnt, int n_events) {
    int i = blockIdx.x * blockDim.x + threadIdx.x;
    int stride = gridDim.x * blockDim.x;
    for (; i < n_events; i += stride) {
        float4 ev = events[i];            // x, y, t, p
        int x = (int)ev.x;                // astype(int32) == trunc
        int y = (int)ev.y;
        bool valid = (x >= 0) & (x < SENSOR_W) & (y >= 0) & (y < SENSOR_H);
        if (valid) {
            int ch = (ev.w > 0.0f) ? 0 : 1;   // pos -> ch 0, neg -> ch 1
            atomicAdd(&cnt[ch * HW + y * SENSOR_W + x], 1u);
        }
    }
}

// Phase 3: convert counters to float and add the base image, in place.
// Each thread touches only its own bin -> no race with itself.
__global__ void finalize_kernel(const float* __restrict__ event_image,
                                float* __restrict__ out, int n) {
    int i = blockIdx.x * blockDim.x + threadIdx.x;
    int stride = gridDim.x * blockDim.x;
    for (; i < n; i += stride) {
        unsigned c = ((const unsigned*)out)[i];
        out[i] = event_image[i] + (float)c;
    }
}

extern "C" void kernel_launch(void* const* d_in, const int* in_sizes, int n_in,
                              void* d_out, int out_size, void* d_ws, size_t ws_size,
                              hipStream_t stream) {
    const float4* events = (const float4*)d_in[0];
    const float* event_image = (const float*)d_in[1];
    float* out = (float*)d_out;

    int n_events = in_sizes[0] / 4;       // N x 4 floats
    int n_out = out_size;                 // 614400

    // 1) zero counters (in d_out, reinterpreted as uint32)
    {
        int block = 256;
        int grid = (n_out + block - 1) / block;
        zero_kernel<<<grid, block, 0, stream>>>((unsigned*)out, n_out);
    }

    // 2) scatter events with native integer atomics
    {
        int block = 256;
        int grid = 2048;                  // grid-stride, 8 wg/CU
        event_scatter_kernel<<<grid, block, 0, stream>>>(events, (unsigned*)out, n_events);
    }

    // 3) counters -> float, add base image
    {
        int block = 256;
        int grid = (n_out + block - 1) / block;
        finalize_kernel<<<grid, block, 0, stream>>>(event_image, out, n_out);
    }
}